// Round 1
// baseline (577.055 us; speedup 1.0000x reference)
//
#include <hip/hip_runtime.h>
#include <hip/hip_bf16.h>

typedef unsigned short u16;
typedef float f32x4 __attribute__((ext_vector_type(4)));
typedef __bf16 bf16x8 __attribute__((ext_vector_type(8)));
typedef u16 u16x8 __attribute__((ext_vector_type(8)));

__device__ __forceinline__ u16 f2bf(float f) {
  unsigned u = __builtin_bit_cast(unsigned, f);
  u = (u + 0x7fffu + ((u >> 16) & 1u)) >> 16;
  return (u16)u;
}

__device__ __forceinline__ void gload16(const void* g, void* l) {
  __builtin_amdgcn_global_load_lds(
      (const __attribute__((address_space(1))) unsigned*)g,
      (__attribute__((address_space(3))) unsigned*)l, 16, 0, 0);
}

// ---------------- convert x (fp32 -> bf16), 8 elems/thread ----------------
__global__ __launch_bounds__(256) void convx(const float4* __restrict__ x,
                                             u16x8* __restrict__ xb, int n) {
  int i = blockIdx.x * 256 + threadIdx.x;
  if (i >= n) return;
  float4 a = x[2 * i], b = x[2 * i + 1];
  u16x8 o;
  o[0] = f2bf(a.x); o[1] = f2bf(a.y); o[2] = f2bf(a.z); o[3] = f2bf(a.w);
  o[4] = f2bf(b.x); o[5] = f2bf(b.y); o[6] = f2bf(b.z); o[7] = f2bf(b.w);
  xb[i] = o;
}

// ------------- transpose weight fp32 [R][C] -> bf16 [C][R] ---------------
__global__ __launch_bounds__(256) void transpose_w(const float* __restrict__ w,
                                                   u16* __restrict__ wt,
                                                   int R, int C) {
  __shared__ float tile[32][33];
  int n0 = blockIdx.x * 32, k0 = blockIdx.y * 32;
  int tx = threadIdx.x & 31, ty = threadIdx.x >> 5;  // ty 0..7
#pragma unroll
  for (int j = 0; j < 32; j += 8)
    tile[ty + j][tx] = w[(size_t)(k0 + ty + j) * C + n0 + tx];
  __syncthreads();
#pragma unroll
  for (int j = 0; j < 32; j += 8)
    wt[(size_t)(n0 + ty + j) * R + k0 + tx] = f2bf(tile[tx][ty + j]);
}

// ---------------- GEMM: C[M][N] = A[M][K] * Bt[N][K]^T -------------------
// MODE 0: bf16 row-major C ; MODE 1: QK scatter ; MODE 2: fp32 row-major C
template <int MODE>
__global__ __launch_bounds__(256) void gemm_bt(const u16* __restrict__ A,
                                               const u16* __restrict__ Bt,
                                               void* __restrict__ Cv,
                                               int M, int N, int K,
                                               u16* __restrict__ Qb,
                                               u16* __restrict__ Kb) {
  __shared__ alignas(16) u16 As[128 * 32];
  __shared__ alignas(16) u16 Bs[128 * 32];
  const int t = threadIdx.x;
  const int lane = t & 63, wid = t >> 6;
  const int wr = wid >> 1, wc = wid & 1;
  const int r = lane & 15, g = lane >> 4;
  const int m0 = blockIdx.y * 128, n0 = blockIdx.x * 128;

  f32x4 acc[4][4] = {};

  const int c0 = wid * 2;  // this wave's two 16-row chunks
  const u16* ga0 = A + (size_t)(m0 + c0 * 16 + (lane >> 2)) * K + (lane & 3) * 8;
  const u16* gb0 = Bt + (size_t)(n0 + c0 * 16 + (lane >> 2)) * K + (lane & 3) * 8;
  const u16* ga1 = ga0 + (size_t)16 * K;
  const u16* gb1 = gb0 + (size_t)16 * K;
  u16* lA0 = &As[c0 * 512];
  u16* lA1 = &As[c0 * 512 + 512];
  u16* lB0 = &Bs[c0 * 512];
  u16* lB1 = &Bs[c0 * 512 + 512];

  for (int k0 = 0; k0 < K; k0 += 32) {
    gload16(ga0 + k0, lA0);
    gload16(ga1 + k0, lA1);
    gload16(gb0 + k0, lB0);
    gload16(gb1 + k0, lB1);
    __syncthreads();
    bf16x8 af[4], bfm[4];
#pragma unroll
    for (int i = 0; i < 4; ++i)
      af[i] = *(const bf16x8*)&As[(wr * 64 + i * 16 + r) * 32 + g * 8];
#pragma unroll
    for (int i = 0; i < 4; ++i)
      bfm[i] = *(const bf16x8*)&Bs[(wc * 64 + i * 16 + r) * 32 + g * 8];
#pragma unroll
    for (int i = 0; i < 4; ++i)
#pragma unroll
      for (int j = 0; j < 4; ++j)
        acc[i][j] = __builtin_amdgcn_mfma_f32_16x16x32_bf16(af[i], bfm[j],
                                                            acc[i][j], 0, 0, 0);
    __syncthreads();
  }

#pragma unroll
  for (int i = 0; i < 4; ++i) {
    int row = m0 + wr * 64 + i * 16 + g * 4;
#pragma unroll
    for (int j = 0; j < 4; ++j) {
      int col = n0 + wc * 64 + j * 16 + r;
#pragma unroll
      for (int e = 0; e < 4; ++e) {
        float v = acc[i][j][e];
        int rr = row + e;
        if (MODE == 0) {
          ((u16*)Cv)[(size_t)rr * N + col] = f2bf(v);
        } else if (MODE == 2) {
          ((float*)Cv)[(size_t)rr * N + col] = v;
        } else {
          int which = col >> 10, hh = (col >> 6) & 15, dd = col & 63;
          int bb = rr >> 11, ss = rr & 2047;
          size_t idx = ((size_t)(bb * 16 + hh) * 2048 + ss) * 64 + dd;
          (which ? Kb : Qb)[idx] = f2bf(v);
        }
      }
    }
  }
}

// ---------------- flash attention, wave-independent ----------------------
// Q,K: [B*H][2048][64] bf16 ; Vt: [1024(h*64+d)][8192(b*2048+s)] bf16
// O: [8192][1024] bf16
__global__ __launch_bounds__(256) void attn_fwd(const u16* __restrict__ Q,
                                                const u16* __restrict__ Kc,
                                                const u16* __restrict__ Vt,
                                                u16* __restrict__ O) {
  __shared__ alignas(16) u16 plds[4][16 * 40];
  const int lane = threadIdx.x & 63, wid = threadIdx.x >> 6;
  const int r = lane & 15, g = lane >> 4;
  const int bh = blockIdx.y;
  const int b = bh >> 4, h = bh & 15;
  const int q0 = blockIdx.x * 64 + wid * 16;

  const u16* Qp = Q + ((size_t)bh * 2048 + q0) * 64;
  const u16* Kp = Kc + (size_t)bh * 2048 * 64;
  const u16* Vp = Vt + (size_t)(h * 64) * 8192 + b * 2048;
  u16* pw = &plds[wid][0];

  bf16x8 qf[2];
  qf[0] = *(const bf16x8*)(Qp + r * 64 + g * 8);
  qf[1] = *(const bf16x8*)(Qp + r * 64 + 32 + g * 8);

  f32x4 o[4] = {};
  float m[4] = {-1e30f, -1e30f, -1e30f, -1e30f};
  float l[4] = {0.f, 0.f, 0.f, 0.f};
  const float CF = 0.125f * 1.44269504088896f;  // SCALE * log2(e)

  for (int kv0 = 0; kv0 < q0 + 16; kv0 += 32) {
    f32x4 s[2];
#pragma unroll
    for (int tt = 0; tt < 2; ++tt) {
      const u16* kp = Kp + (size_t)(kv0 + tt * 16 + r) * 64 + g * 8;
      bf16x8 k0f = *(const bf16x8*)kp;
      bf16x8 k1f = *(const bf16x8*)(kp + 32);
      f32x4 z = {};
      z = __builtin_amdgcn_mfma_f32_16x16x32_bf16(qf[0], k0f, z, 0, 0, 0);
      z = __builtin_amdgcn_mfma_f32_16x16x32_bf16(qf[1], k1f, z, 0, 0, 0);
      s[tt] = z;
    }
    if (kv0 + 32 > q0) {  // only diagonal tiles need masking
#pragma unroll
      for (int tt = 0; tt < 2; ++tt) {
        int col = kv0 + tt * 16 + r;
#pragma unroll
        for (int e = 0; e < 4; ++e)
          if (col > q0 + g * 4 + e) s[tt][e] = -1e30f;
      }
    }
    float pm[4], sf[4], rs[4];
#pragma unroll
    for (int e = 0; e < 4; ++e) pm[e] = fmaxf(s[0][e], s[1][e]);
#pragma unroll
    for (int e = 0; e < 4; ++e) {
      pm[e] = fmaxf(pm[e], __shfl_xor(pm[e], 1));
      pm[e] = fmaxf(pm[e], __shfl_xor(pm[e], 2));
      pm[e] = fmaxf(pm[e], __shfl_xor(pm[e], 4));
      pm[e] = fmaxf(pm[e], __shfl_xor(pm[e], 8));
    }
#pragma unroll
    for (int e = 0; e < 4; ++e) {
      float mn = fmaxf(m[e], pm[e]);
      sf[e] = exp2f((m[e] - mn) * CF);
      m[e] = mn;
      rs[e] = 0.f;
    }
#pragma unroll
    for (int tt = 0; tt < 2; ++tt)
#pragma unroll
      for (int e = 0; e < 4; ++e) {
        float p = exp2f((s[tt][e] - m[e]) * CF);
        rs[e] += p;
        pw[(g * 4 + e) * 40 + tt * 16 + r] = f2bf(p);
      }
#pragma unroll
    for (int e = 0; e < 4; ++e) {
      rs[e] += __shfl_xor(rs[e], 1);
      rs[e] += __shfl_xor(rs[e], 2);
      rs[e] += __shfl_xor(rs[e], 4);
      rs[e] += __shfl_xor(rs[e], 8);
      l[e] = l[e] * sf[e] + rs[e];
      o[0][e] *= sf[e];
      o[1][e] *= sf[e];
      o[2][e] *= sf[e];
      o[3][e] *= sf[e];
    }
    bf16x8 pf = *(const bf16x8*)&pw[r * 40 + g * 8];
#pragma unroll
    for (int dt = 0; dt < 4; ++dt) {
      bf16x8 vf = *(const bf16x8*)(Vp + (size_t)(dt * 16 + r) * 8192 + kv0 + g * 8);
      o[dt] = __builtin_amdgcn_mfma_f32_16x16x32_bf16(pf, vf, o[dt], 0, 0, 0);
    }
  }
#pragma unroll
  for (int dt = 0; dt < 4; ++dt)
#pragma unroll
    for (int e = 0; e < 4; ++e)
      O[((size_t)b * 2048 + q0 + g * 4 + e) * 1024 + h * 64 + dt * 16 + r] =
          f2bf(o[dt][e] / l[e]);
}

extern "C" void kernel_launch(void* const* d_in, const int* in_sizes, int n_in,
                              void* d_out, int out_size, void* d_ws,
                              size_t ws_size, hipStream_t stream) {
  const float* x = (const float*)d_in[0];
  const float* wqkv = (const float*)d_in[1];
  const float* wout = (const float*)d_in[2];
  float* out = (float*)d_out;
  char* ws = (char*)d_ws;

  // workspace layout (bytes)
  u16* Xb = (u16*)ws;                          // 16 MB [8192][1024] (later: attn out)
  u16* Wt = (u16*)(ws + (22ull << 20) - (6ull << 20));   // at 16 MB, 6 MB [3072][1024]
  u16* WoT = (u16*)(ws + (22ull << 20));       // 2 MB [1024][1024]
  u16* Qb = (u16*)(ws + (24ull << 20));        // 16 MB [B*H][2048][64]
  u16* Kb = (u16*)(ws + (40ull << 20));        // 16 MB
  u16* Vt = (u16*)(ws + (56ull << 20));        // 16 MB [1024][8192]

  convx<<<4096, 256, 0, stream>>>((const float4*)x, (u16x8*)Xb, 1048576);
  transpose_w<<<dim3(96, 32), 256, 0, stream>>>(wqkv, Wt, 1024, 3072);
  transpose_w<<<dim3(32, 32), 256, 0, stream>>>(wout, WoT, 1024, 1024);

  // Q,K: [8192,1024] x [1024,2048] -> scatter
  gemm_bt<1><<<dim3(16, 64), 256, 0, stream>>>(Xb, Wt, nullptr, 8192, 2048,
                                               1024, Qb, Kb);
  // V^T: Wv^T [1024,1024] x Xb^T -> Vt [1024][8192]
  gemm_bt<0><<<dim3(64, 8), 256, 0, stream>>>(Wt + (size_t)2048 * 1024, Xb, Vt,
                                              1024, 8192, 1024, nullptr, nullptr);
  // attention; writes bf16 attn output into Xb (dead after V-GEMM)
  attn_fwd<<<dim3(32, 64), 256, 0, stream>>>(Qb, Kb, Vt, Xb);
  // out = attn @ w_out : [8192,1024] x [1024,1024] -> fp32
  gemm_bt<2><<<dim3(8, 64), 256, 0, stream>>>(Xb, WoT, out, 8192, 1024, 1024,
                                              nullptr, nullptr);
}

// Round 2
// 350.324 us; speedup vs baseline: 1.6472x; 1.6472x over previous
//
#include <hip/hip_runtime.h>
#include <hip/hip_bf16.h>

typedef unsigned short u16;
typedef float f32x4 __attribute__((ext_vector_type(4)));
typedef __bf16 bf16x8 __attribute__((ext_vector_type(8)));
typedef u16 u16x8 __attribute__((ext_vector_type(8)));

__device__ __forceinline__ u16 f2bf(float f) {
  unsigned u = __builtin_bit_cast(unsigned, f);
  u = (u + 0x7fffu + ((u >> 16) & 1u)) >> 16;
  return (u16)u;
}

__device__ __forceinline__ void gload16(const void* g, void* l) {
  __builtin_amdgcn_global_load_lds(
      (const __attribute__((address_space(1))) unsigned*)g,
      (__attribute__((address_space(3))) unsigned*)l, 16, 0, 0);
}

// ---------------- convert x (fp32 -> bf16), 8 elems/thread ----------------
__global__ __launch_bounds__(256) void convx(const float4* __restrict__ x,
                                             u16x8* __restrict__ xb, int n) {
  int i = blockIdx.x * 256 + threadIdx.x;
  if (i >= n) return;
  float4 a = x[2 * i], b = x[2 * i + 1];
  u16x8 o;
  o[0] = f2bf(a.x); o[1] = f2bf(a.y); o[2] = f2bf(a.z); o[3] = f2bf(a.w);
  o[4] = f2bf(b.x); o[5] = f2bf(b.y); o[6] = f2bf(b.z); o[7] = f2bf(b.w);
  xb[i] = o;
}

// ------------- transpose weight fp32 [R][C] -> bf16 [C][R] ---------------
__global__ __launch_bounds__(256) void transpose_w(const float* __restrict__ w,
                                                   u16* __restrict__ wt,
                                                   int R, int C) {
  __shared__ float tile[32][33];
  int n0 = blockIdx.x * 32, k0 = blockIdx.y * 32;
  int tx = threadIdx.x & 31, ty = threadIdx.x >> 5;  // ty 0..7
#pragma unroll
  for (int j = 0; j < 32; j += 8)
    tile[ty + j][tx] = w[(size_t)(k0 + ty + j) * C + n0 + tx];
  __syncthreads();
#pragma unroll
  for (int j = 0; j < 32; j += 8)
    wt[(size_t)(n0 + ty + j) * R + k0 + tx] = f2bf(tile[tx][ty + j]);
}

// ---------------- GEMM: C[M][N] = A[M][K] * Bt[N][K]^T -------------------
// MODE 0: bf16 row-major C ; MODE 1: QK scatter ; MODE 2: fp32 row-major C
template <int MODE>
__global__ __launch_bounds__(256) void gemm_bt(const u16* __restrict__ A,
                                               const u16* __restrict__ Bt,
                                               void* __restrict__ Cv,
                                               int M, int N, int K,
                                               u16* __restrict__ Qb,
                                               u16* __restrict__ Kb) {
  __shared__ alignas(16) u16 As[128 * 32];
  __shared__ alignas(16) u16 Bs[128 * 32];
  const int t = threadIdx.x;
  const int lane = t & 63, wid = t >> 6;
  const int wr = wid >> 1, wc = wid & 1;
  const int r = lane & 15, g = lane >> 4;
  const int m0 = blockIdx.y * 128, n0 = blockIdx.x * 128;

  f32x4 acc[4][4] = {};

  const int c0 = wid * 2;  // this wave's two 16-row chunks
  const u16* ga0 = A + (size_t)(m0 + c0 * 16 + (lane >> 2)) * K + (lane & 3) * 8;
  const u16* gb0 = Bt + (size_t)(n0 + c0 * 16 + (lane >> 2)) * K + (lane & 3) * 8;
  const u16* ga1 = ga0 + (size_t)16 * K;
  const u16* gb1 = gb0 + (size_t)16 * K;
  u16* lA0 = &As[c0 * 512];
  u16* lA1 = &As[c0 * 512 + 512];
  u16* lB0 = &Bs[c0 * 512];
  u16* lB1 = &Bs[c0 * 512 + 512];

  for (int k0 = 0; k0 < K; k0 += 32) {
    gload16(ga0 + k0, lA0);
    gload16(ga1 + k0, lA1);
    gload16(gb0 + k0, lB0);
    gload16(gb1 + k0, lB1);
    __syncthreads();
    bf16x8 af[4], bfm[4];
#pragma unroll
    for (int i = 0; i < 4; ++i)
      af[i] = *(const bf16x8*)&As[(wr * 64 + i * 16 + r) * 32 + g * 8];
#pragma unroll
    for (int i = 0; i < 4; ++i)
      bfm[i] = *(const bf16x8*)&Bs[(wc * 64 + i * 16 + r) * 32 + g * 8];
#pragma unroll
    for (int i = 0; i < 4; ++i)
#pragma unroll
      for (int j = 0; j < 4; ++j)
        acc[i][j] = __builtin_amdgcn_mfma_f32_16x16x32_bf16(af[i], bfm[j],
                                                            acc[i][j], 0, 0, 0);
    __syncthreads();
  }

#pragma unroll
  for (int i = 0; i < 4; ++i) {
    int row = m0 + wr * 64 + i * 16 + g * 4;
#pragma unroll
    for (int j = 0; j < 4; ++j) {
      int col = n0 + wc * 64 + j * 16 + r;
#pragma unroll
      for (int e = 0; e < 4; ++e) {
        float v = acc[i][j][e];
        int rr = row + e;
        if (MODE == 0) {
          ((u16*)Cv)[(size_t)rr * N + col] = f2bf(v);
        } else if (MODE == 2) {
          ((float*)Cv)[(size_t)rr * N + col] = v;
        } else {
          int which = col >> 10, hh = (col >> 6) & 15, dd = col & 63;
          int bb = rr >> 11, ss = rr & 2047;
          size_t idx = ((size_t)(bb * 16 + hh) * 2048 + ss) * 64 + dd;
          (which ? Kb : Qb)[idx] = f2bf(v);
        }
      }
    }
  }
}

// ---------------- flash attention, block-staged K/V ----------------------
// Q,K: [B*H][2048][64] bf16 ; Vt: [1024(h*64+d)][8192(b*2048+s)] bf16
// O: [8192][1024] bf16
// Block: 4 waves, 128 q-rows (32/wave). KVB=64, K/V double-buffered in LDS
// (global_load_lds, source-XOR swizzled so frag reads are 8-way not 16-way).
__global__ __launch_bounds__(256, 3) void attn_fwd(const u16* __restrict__ Q,
                                                   const u16* __restrict__ Kc,
                                                   const u16* __restrict__ Vt,
                                                   u16* __restrict__ O) {
  __shared__ alignas(16) u16 Ks[2][64][64];
  __shared__ alignas(16) u16 Vs[2][64][64];
  __shared__ alignas(16) u16 Ps[4][32][72];
  const int lane = threadIdx.x & 63, wid = threadIdx.x >> 6;
  const int r = lane & 15, g = lane >> 4;
  const int bh = blockIdx.y, b = bh >> 4, h = bh & 15;
  const int qb = (int)gridDim.x - 1 - (int)blockIdx.x;  // heavy blocks first
  const int qw = qb * 128 + wid * 32;
  const int wmax = qw + 31;

  const u16* Qp = Q + ((size_t)bh * 2048 + qw) * 64;
  const u16* Kp = Kc + (size_t)bh * 2048 * 64;
  const u16* Vp = Vt + (size_t)(h * 64) * 8192 + (size_t)b * 2048;
  u16* pw = &Ps[wid][0][0];

  const int srow = lane >> 3;                // 0..7
  const int scol = ((lane & 7) ^ srow) * 8;  // pre-swizzled source col (elems)

  bf16x8 qf[2][2];
#pragma unroll
  for (int i = 0; i < 2; ++i)
#pragma unroll
    for (int ks = 0; ks < 2; ++ks)
      qf[i][ks] = *(const bf16x8*)(Qp + (size_t)(i * 16 + r) * 64 + ks * 32 + g * 8);

  f32x4 o[2][4] = {};
  float m[2][4], l[2][4];
#pragma unroll
  for (int i = 0; i < 2; ++i)
#pragma unroll
    for (int e = 0; e < 4; ++e) { m[i][e] = -1e30f; l[i][e] = 0.f; }

  const float CF = 0.125f * 1.44269504088896f;  // SCALE * log2(e)
  const int nkv = 2 * (qb + 1);

  // stage tile 0 into buffer 0 (each wave stages 16 rows of K and V)
  gload16(Kp + (size_t)(wid * 16 + srow) * 64 + scol, &Ks[0][wid * 16][0]);
  gload16(Kp + (size_t)(wid * 16 + 8 + srow) * 64 + scol, &Ks[0][wid * 16 + 8][0]);
  gload16(Vp + (size_t)(wid * 16 + srow) * 8192 + scol, &Vs[0][wid * 16][0]);
  gload16(Vp + (size_t)(wid * 16 + 8 + srow) * 8192 + scol, &Vs[0][wid * 16 + 8][0]);

  int cur = 0;
  for (int t = 0; t < nkv; ++t, cur ^= 1) {
    __syncthreads();  // tile t resident; all waves done with buffer cur^1
    if (t + 1 < nkv) {  // prefetch tile t+1 into the other buffer (async)
      const int kn = (t + 1) * 64;
      gload16(Kp + (size_t)(kn + wid * 16 + srow) * 64 + scol, &Ks[cur ^ 1][wid * 16][0]);
      gload16(Kp + (size_t)(kn + wid * 16 + 8 + srow) * 64 + scol, &Ks[cur ^ 1][wid * 16 + 8][0]);
      gload16(Vp + (size_t)(wid * 16 + srow) * 8192 + kn + scol, &Vs[cur ^ 1][wid * 16][0]);
      gload16(Vp + (size_t)(wid * 16 + 8 + srow) * 8192 + kn + scol, &Vs[cur ^ 1][wid * 16 + 8][0]);
    }
    const int kv0 = t * 64;
    if (kv0 > wmax) continue;  // wave-uniform: this wave fully masked here

    // ---- QK^T: 32q x 64kv, K=64 ----
    f32x4 s[2][4];
#pragma unroll
    for (int tt = 0; tt < 4; ++tt) {
      bf16x8 k0 = *(const bf16x8*)&Ks[cur][tt * 16 + r][((0 + g) ^ (r & 7)) * 8];
      bf16x8 k1 = *(const bf16x8*)&Ks[cur][tt * 16 + r][((4 + g) ^ (r & 7)) * 8];
#pragma unroll
      for (int i = 0; i < 2; ++i) {
        f32x4 z = {};
        z = __builtin_amdgcn_mfma_f32_16x16x32_bf16(qf[i][0], k0, z, 0, 0, 0);
        z = __builtin_amdgcn_mfma_f32_16x16x32_bf16(qf[i][1], k1, z, 0, 0, 0);
        s[i][tt] = z;
      }
    }
    if (kv0 + 63 > qw) {  // diagonal-crossing tiles: causal mask
#pragma unroll
      for (int tt = 0; tt < 4; ++tt) {
        int col = kv0 + tt * 16 + r;
#pragma unroll
        for (int i = 0; i < 2; ++i)
#pragma unroll
          for (int e = 0; e < 4; ++e)
            if (col > qw + i * 16 + g * 4 + e) s[i][tt][e] = -1e30f;
      }
    }

    // ---- online softmax ----
    float sf[2][4];
#pragma unroll
    for (int i = 0; i < 2; ++i)
#pragma unroll
      for (int e = 0; e < 4; ++e) {
        float pm = fmaxf(fmaxf(s[i][0][e], s[i][1][e]), fmaxf(s[i][2][e], s[i][3][e]));
        pm = fmaxf(pm, __shfl_xor(pm, 1));
        pm = fmaxf(pm, __shfl_xor(pm, 2));
        pm = fmaxf(pm, __shfl_xor(pm, 4));
        pm = fmaxf(pm, __shfl_xor(pm, 8));
        float mn = fmaxf(m[i][e], pm);
        sf[i][e] = exp2f((m[i][e] - mn) * CF);
        m[i][e] = mn;
      }
    float rs[2][4] = {};
#pragma unroll
    for (int i = 0; i < 2; ++i)
#pragma unroll
      for (int tt = 0; tt < 4; ++tt)
#pragma unroll
        for (int e = 0; e < 4; ++e) {
          float p = exp2f((s[i][tt][e] - m[i][e]) * CF);
          rs[i][e] += p;
          pw[(i * 16 + g * 4 + e) * 72 + tt * 16 + r] = f2bf(p);
        }
#pragma unroll
    for (int i = 0; i < 2; ++i)
#pragma unroll
      for (int e = 0; e < 4; ++e) {
        float t2 = rs[i][e];
        t2 += __shfl_xor(t2, 1);
        t2 += __shfl_xor(t2, 2);
        t2 += __shfl_xor(t2, 4);
        t2 += __shfl_xor(t2, 8);
        l[i][e] = l[i][e] * sf[i][e] + t2;
#pragma unroll
        for (int dt = 0; dt < 4; ++dt) o[i][dt][e] *= sf[i][e];
      }

    // ---- PV: O[32q][64d] += P[32q][64kv] * V[64kv][64d] ----
    bf16x8 pf[2][2];
#pragma unroll
    for (int i = 0; i < 2; ++i)
#pragma unroll
      for (int ks = 0; ks < 2; ++ks)
        pf[i][ks] = *(const bf16x8*)&pw[(i * 16 + r) * 72 + ks * 32 + g * 8];
#pragma unroll
    for (int dt = 0; dt < 4; ++dt) {
      bf16x8 v0 = *(const bf16x8*)&Vs[cur][dt * 16 + r][((0 + g) ^ (r & 7)) * 8];
      bf16x8 v1 = *(const bf16x8*)&Vs[cur][dt * 16 + r][((4 + g) ^ (r & 7)) * 8];
#pragma unroll
      for (int i = 0; i < 2; ++i) {
        o[i][dt] = __builtin_amdgcn_mfma_f32_16x16x32_bf16(pf[i][0], v0, o[i][dt], 0, 0, 0);
        o[i][dt] = __builtin_amdgcn_mfma_f32_16x16x32_bf16(pf[i][1], v1, o[i][dt], 0, 0, 0);
      }
    }
  }

#pragma unroll
  for (int i = 0; i < 2; ++i)
#pragma unroll
    for (int dt = 0; dt < 4; ++dt)
#pragma unroll
      for (int e = 0; e < 4; ++e)
        O[((size_t)b * 2048 + qw + i * 16 + g * 4 + e) * 1024 + h * 64 + dt * 16 + r] =
            f2bf(o[i][dt][e] / l[i][e]);
}

extern "C" void kernel_launch(void* const* d_in, const int* in_sizes, int n_in,
                              void* d_out, int out_size, void* d_ws,
                              size_t ws_size, hipStream_t stream) {
  const float* x = (const float*)d_in[0];
  const float* wqkv = (const float*)d_in[1];
  const float* wout = (const float*)d_in[2];
  float* out = (float*)d_out;
  char* ws = (char*)d_ws;

  // workspace layout (bytes)
  u16* Xb = (u16*)ws;                          // 16 MB [8192][1024] (later: attn out)
  u16* Wt = (u16*)(ws + (16ull << 20));        // 6 MB [3072][1024]
  u16* WoT = (u16*)(ws + (22ull << 20));       // 2 MB [1024][1024]
  u16* Qb = (u16*)(ws + (24ull << 20));        // 16 MB [B*H][2048][64]
  u16* Kb = (u16*)(ws + (40ull << 20));        // 16 MB
  u16* Vt = (u16*)(ws + (56ull << 20));        // 16 MB [1024][8192]

  convx<<<4096, 256, 0, stream>>>((const float4*)x, (u16x8*)Xb, 1048576);
  transpose_w<<<dim3(96, 32), 256, 0, stream>>>(wqkv, Wt, 1024, 3072);
  transpose_w<<<dim3(32, 32), 256, 0, stream>>>(wout, WoT, 1024, 1024);

  // Q,K: [8192,1024] x [1024,2048] -> scatter
  gemm_bt<1><<<dim3(16, 64), 256, 0, stream>>>(Xb, Wt, nullptr, 8192, 2048,
                                               1024, Qb, Kb);
  // V^T: Wv^T [1024,1024] x Xb^T -> Vt [1024][8192]
  gemm_bt<0><<<dim3(64, 8), 256, 0, stream>>>(Wt + (size_t)2048 * 1024, Xb, Vt,
                                              1024, 8192, 1024, nullptr, nullptr);
  // attention; writes bf16 attn output into Xb (dead after V-GEMM)
  attn_fwd<<<dim3(16, 64), 256, 0, stream>>>(Qb, Kb, Vt, Xb);
  // out = attn @ w_out : [8192,1024] x [1024,1024] -> fp32
  gemm_bt<2><<<dim3(8, 64), 256, 0, stream>>>(Xb, WoT, out, 8192, 1024, 1024,
                                              nullptr, nullptr);
}

// Round 3
// 289.078 us; speedup vs baseline: 1.9962x; 1.2119x over previous
//
#include <hip/hip_runtime.h>
#include <hip/hip_bf16.h>

typedef unsigned short u16;
typedef float f32x4 __attribute__((ext_vector_type(4)));
typedef __bf16 bf16x8 __attribute__((ext_vector_type(8)));
typedef u16 u16x8 __attribute__((ext_vector_type(8)));

__device__ __forceinline__ u16 f2bf(float f) {
  unsigned u = __builtin_bit_cast(unsigned, f);
  u = (u + 0x7fffu + ((u >> 16) & 1u)) >> 16;
  return (u16)u;
}

__device__ __forceinline__ void gload16(const void* g, void* l) {
  __builtin_amdgcn_global_load_lds(
      (const __attribute__((address_space(1))) unsigned*)g,
      (__attribute__((address_space(3))) unsigned*)l, 16, 0, 0);
}

// ---------------- convert x (fp32 -> bf16), 8 elems/thread ----------------
__global__ __launch_bounds__(256) void convx(const float4* __restrict__ x,
                                             u16x8* __restrict__ xb, int n) {
  int i = blockIdx.x * 256 + threadIdx.x;
  if (i >= n) return;
  float4 a = x[2 * i], b = x[2 * i + 1];
  u16x8 o;
  o[0] = f2bf(a.x); o[1] = f2bf(a.y); o[2] = f2bf(a.z); o[3] = f2bf(a.w);
  o[4] = f2bf(b.x); o[5] = f2bf(b.y); o[6] = f2bf(b.z); o[7] = f2bf(b.w);
  xb[i] = o;
}

// ------------- transpose weight fp32 [R][C] -> bf16 [C][R] ---------------
__global__ __launch_bounds__(256) void transpose_w(const float* __restrict__ w,
                                                   u16* __restrict__ wt,
                                                   int R, int C) {
  __shared__ float tile[32][33];
  int n0 = blockIdx.x * 32, k0 = blockIdx.y * 32;
  int tx = threadIdx.x & 31, ty = threadIdx.x >> 5;  // ty 0..7
#pragma unroll
  for (int j = 0; j < 32; j += 8)
    tile[ty + j][tx] = w[(size_t)(k0 + ty + j) * C + n0 + tx];
  __syncthreads();
#pragma unroll
  for (int j = 0; j < 32; j += 8)
    wt[(size_t)(n0 + ty + j) * R + k0 + tx] = f2bf(tile[tx][ty + j]);
}

// ---------------- GEMM: C[M][N] = A[M][K] * Bt[N][K]^T -------------------
// MODE 0: bf16 row-major C ; MODE 1: QK scatter ; MODE 2: fp32 row-major C
template <int MODE>
__global__ __launch_bounds__(256) void gemm_bt(const u16* __restrict__ A,
                                               const u16* __restrict__ Bt,
                                               void* __restrict__ Cv,
                                               int M, int N, int K,
                                               u16* __restrict__ Qb,
                                               u16* __restrict__ Kb) {
  __shared__ alignas(16) u16 As[128 * 32];
  __shared__ alignas(16) u16 Bs[128 * 32];
  const int t = threadIdx.x;
  const int lane = t & 63, wid = t >> 6;
  const int wr = wid >> 1, wc = wid & 1;
  const int r = lane & 15, g = lane >> 4;
  const int m0 = blockIdx.y * 128, n0 = blockIdx.x * 128;

  f32x4 acc[4][4] = {};

  const int c0 = wid * 2;  // this wave's two 16-row chunks
  const u16* ga0 = A + (size_t)(m0 + c0 * 16 + (lane >> 2)) * K + (lane & 3) * 8;
  const u16* gb0 = Bt + (size_t)(n0 + c0 * 16 + (lane >> 2)) * K + (lane & 3) * 8;
  const u16* ga1 = ga0 + (size_t)16 * K;
  const u16* gb1 = gb0 + (size_t)16 * K;
  u16* lA0 = &As[c0 * 512];
  u16* lA1 = &As[c0 * 512 + 512];
  u16* lB0 = &Bs[c0 * 512];
  u16* lB1 = &Bs[c0 * 512 + 512];

  for (int k0 = 0; k0 < K; k0 += 32) {
    gload16(ga0 + k0, lA0);
    gload16(ga1 + k0, lA1);
    gload16(gb0 + k0, lB0);
    gload16(gb1 + k0, lB1);
    __syncthreads();
    bf16x8 af[4], bfm[4];
#pragma unroll
    for (int i = 0; i < 4; ++i)
      af[i] = *(const bf16x8*)&As[(wr * 64 + i * 16 + r) * 32 + g * 8];
#pragma unroll
    for (int i = 0; i < 4; ++i)
      bfm[i] = *(const bf16x8*)&Bs[(wc * 64 + i * 16 + r) * 32 + g * 8];
#pragma unroll
    for (int i = 0; i < 4; ++i)
#pragma unroll
      for (int j = 0; j < 4; ++j)
        acc[i][j] = __builtin_amdgcn_mfma_f32_16x16x32_bf16(af[i], bfm[j],
                                                            acc[i][j], 0, 0, 0);
    __syncthreads();
  }

#pragma unroll
  for (int i = 0; i < 4; ++i) {
    int row = m0 + wr * 64 + i * 16 + g * 4;
#pragma unroll
    for (int j = 0; j < 4; ++j) {
      int col = n0 + wc * 64 + j * 16 + r;
#pragma unroll
      for (int e = 0; e < 4; ++e) {
        float v = acc[i][j][e];
        int rr = row + e;
        if (MODE == 0) {
          ((u16*)Cv)[(size_t)rr * N + col] = f2bf(v);
        } else if (MODE == 2) {
          ((float*)Cv)[(size_t)rr * N + col] = v;
        } else {
          int which = col >> 10, hh = (col >> 6) & 15, dd = col & 63;
          int bb = rr >> 11, ss = rr & 2047;
          size_t idx = ((size_t)(bb * 16 + hh) * 2048 + ss) * 64 + dd;
          (which ? Kb : Qb)[idx] = f2bf(v);
        }
      }
    }
  }
}

// ---------------- flash attention, block-staged K/V, paired q-tiles -------
// Q,K: [B*H][2048][64] bf16 ; Vt: [1024(h*64+d)][8192(b*2048+s)] bf16
// O: [8192][1024] bf16
// Block: 4 waves, 128 q-rows (32/wave). KVB=64, K/V double-buffered in LDS.
// Causal load balance: block qbp handles q-tile (15-qbp) then q-tile qbp,
// so every block does exactly 17 kv-tiles of work -> flat occupancy.
__global__ __launch_bounds__(256, 3) void attn_fwd(const u16* __restrict__ Q,
                                                   const u16* __restrict__ Kc,
                                                   const u16* __restrict__ Vt,
                                                   u16* __restrict__ O) {
  __shared__ alignas(16) u16 Ks[2][64][64];
  __shared__ alignas(16) u16 Vs[2][64][64];
  __shared__ alignas(16) u16 Ps[4][32][72];
  const int lane = threadIdx.x & 63, wid = threadIdx.x >> 6;
  const int r = lane & 15, g = lane >> 4;
  const int bh = blockIdx.y, b = bh >> 4, h = bh & 15;

  const u16* Kp = Kc + (size_t)bh * 2048 * 64;
  const u16* Vp = Vt + (size_t)(h * 64) * 8192 + (size_t)b * 2048;
  u16* pw = &Ps[wid][0][0];

  const int srow = lane >> 3;                // 0..7
  const int scol = ((lane & 7) ^ srow) * 8;  // pre-swizzled source col (elems)
  const float CF = 0.125f * 1.44269504088896f;  // SCALE * log2(e)

  for (int pass = 0; pass < 2; ++pass) {
    const int qb = pass ? (int)blockIdx.x : 15 - (int)blockIdx.x;
    const int qw = qb * 128 + wid * 32;
    const int wmax = qw + 31;
    const int nkv = 2 * (qb + 1);
    const u16* Qp = Q + ((size_t)bh * 2048 + qw) * 64;

    bf16x8 qf[2][2];
#pragma unroll
    for (int i = 0; i < 2; ++i)
#pragma unroll
      for (int ks = 0; ks < 2; ++ks)
        qf[i][ks] = *(const bf16x8*)(Qp + (size_t)(i * 16 + r) * 64 + ks * 32 + g * 8);

    f32x4 o[2][4] = {};
    float m[2][4], l[2][4];
#pragma unroll
    for (int i = 0; i < 2; ++i)
#pragma unroll
      for (int e = 0; e < 4; ++e) { m[i][e] = -1e30f; l[i][e] = 0.f; }

    __syncthreads();  // previous pass done with all LDS buffers

    // stage tile 0 into buffer 0 (each wave stages 16 rows of K and V)
    gload16(Kp + (size_t)(wid * 16 + srow) * 64 + scol, &Ks[0][wid * 16][0]);
    gload16(Kp + (size_t)(wid * 16 + 8 + srow) * 64 + scol, &Ks[0][wid * 16 + 8][0]);
    gload16(Vp + (size_t)(wid * 16 + srow) * 8192 + scol, &Vs[0][wid * 16][0]);
    gload16(Vp + (size_t)(wid * 16 + 8 + srow) * 8192 + scol, &Vs[0][wid * 16 + 8][0]);

    int cur = 0;
    for (int t = 0; t < nkv; ++t, cur ^= 1) {
      __syncthreads();  // tile t resident; all waves done with buffer cur^1
      if (t + 1 < nkv) {  // prefetch tile t+1 into the other buffer (async)
        const int kn = (t + 1) * 64;
        gload16(Kp + (size_t)(kn + wid * 16 + srow) * 64 + scol, &Ks[cur ^ 1][wid * 16][0]);
        gload16(Kp + (size_t)(kn + wid * 16 + 8 + srow) * 64 + scol, &Ks[cur ^ 1][wid * 16 + 8][0]);
        gload16(Vp + (size_t)(wid * 16 + srow) * 8192 + kn + scol, &Vs[cur ^ 1][wid * 16][0]);
        gload16(Vp + (size_t)(wid * 16 + 8 + srow) * 8192 + kn + scol, &Vs[cur ^ 1][wid * 16 + 8][0]);
      }
      const int kv0 = t * 64;
      if (kv0 > wmax) continue;  // wave-uniform: this wave fully masked here

      // ---- QK^T: 32q x 64kv, K=64 ----
      f32x4 s[2][4];
#pragma unroll
      for (int tt = 0; tt < 4; ++tt) {
        bf16x8 k0 = *(const bf16x8*)&Ks[cur][tt * 16 + r][((0 + g) ^ (r & 7)) * 8];
        bf16x8 k1 = *(const bf16x8*)&Ks[cur][tt * 16 + r][((4 + g) ^ (r & 7)) * 8];
#pragma unroll
        for (int i = 0; i < 2; ++i) {
          f32x4 z = {};
          z = __builtin_amdgcn_mfma_f32_16x16x32_bf16(qf[i][0], k0, z, 0, 0, 0);
          z = __builtin_amdgcn_mfma_f32_16x16x32_bf16(qf[i][1], k1, z, 0, 0, 0);
          s[i][tt] = z;
        }
      }
      if (kv0 + 63 > qw) {  // diagonal-crossing tiles: causal mask
#pragma unroll
        for (int tt = 0; tt < 4; ++tt) {
          int col = kv0 + tt * 16 + r;
#pragma unroll
          for (int i = 0; i < 2; ++i)
#pragma unroll
            for (int e = 0; e < 4; ++e)
              if (col > qw + i * 16 + g * 4 + e) s[i][tt][e] = -1e30f;
        }
      }

      // ---- online softmax ----
      float sf[2][4];
#pragma unroll
      for (int i = 0; i < 2; ++i)
#pragma unroll
        for (int e = 0; e < 4; ++e) {
          float pm = fmaxf(fmaxf(s[i][0][e], s[i][1][e]), fmaxf(s[i][2][e], s[i][3][e]));
          pm = fmaxf(pm, __shfl_xor(pm, 1));
          pm = fmaxf(pm, __shfl_xor(pm, 2));
          pm = fmaxf(pm, __shfl_xor(pm, 4));
          pm = fmaxf(pm, __shfl_xor(pm, 8));
          float mn = fmaxf(m[i][e], pm);
          sf[i][e] = exp2f((m[i][e] - mn) * CF);
          m[i][e] = mn;
        }
      float rs[2][4] = {};
#pragma unroll
      for (int i = 0; i < 2; ++i)
#pragma unroll
        for (int tt = 0; tt < 4; ++tt)
#pragma unroll
          for (int e = 0; e < 4; ++e) {
            float p = exp2f((s[i][tt][e] - m[i][e]) * CF);
            rs[i][e] += p;
            pw[(i * 16 + g * 4 + e) * 72 + tt * 16 + r] = f2bf(p);
          }
#pragma unroll
      for (int i = 0; i < 2; ++i)
#pragma unroll
        for (int e = 0; e < 4; ++e) {
          float t2 = rs[i][e];
          t2 += __shfl_xor(t2, 1);
          t2 += __shfl_xor(t2, 2);
          t2 += __shfl_xor(t2, 4);
          t2 += __shfl_xor(t2, 8);
          l[i][e] = l[i][e] * sf[i][e] + t2;
#pragma unroll
          for (int dt = 0; dt < 4; ++dt) o[i][dt][e] *= sf[i][e];
        }

      // ---- PV: O[32q][64d] += P[32q][64kv] * V[64kv][64d] ----
      bf16x8 pf[2][2];
#pragma unroll
      for (int i = 0; i < 2; ++i)
#pragma unroll
        for (int ks = 0; ks < 2; ++ks)
          pf[i][ks] = *(const bf16x8*)&pw[(i * 16 + r) * 72 + ks * 32 + g * 8];
#pragma unroll
      for (int dt = 0; dt < 4; ++dt) {
        bf16x8 v0 = *(const bf16x8*)&Vs[cur][dt * 16 + r][((0 + g) ^ (r & 7)) * 8];
        bf16x8 v1 = *(const bf16x8*)&Vs[cur][dt * 16 + r][((4 + g) ^ (r & 7)) * 8];
#pragma unroll
        for (int i = 0; i < 2; ++i) {
          o[i][dt] = __builtin_amdgcn_mfma_f32_16x16x32_bf16(pf[i][0], v0, o[i][dt], 0, 0, 0);
          o[i][dt] = __builtin_amdgcn_mfma_f32_16x16x32_bf16(pf[i][1], v1, o[i][dt], 0, 0, 0);
        }
      }
    }

#pragma unroll
    for (int i = 0; i < 2; ++i)
#pragma unroll
      for (int dt = 0; dt < 4; ++dt)
#pragma unroll
        for (int e = 0; e < 4; ++e)
          O[((size_t)b * 2048 + qw + i * 16 + g * 4 + e) * 1024 + h * 64 + dt * 16 + r] =
              f2bf(o[i][dt][e] / l[i][e]);
  }
}

extern "C" void kernel_launch(void* const* d_in, const int* in_sizes, int n_in,
                              void* d_out, int out_size, void* d_ws,
                              size_t ws_size, hipStream_t stream) {
  const float* x = (const float*)d_in[0];
  const float* wqkv = (const float*)d_in[1];
  const float* wout = (const float*)d_in[2];
  float* out = (float*)d_out;
  char* ws = (char*)d_ws;

  // workspace layout (bytes)
  u16* Xb = (u16*)ws;                          // 16 MB [8192][1024] (later: attn out)
  u16* Wt = (u16*)(ws + (16ull << 20));        // 6 MB [3072][1024]
  u16* WoT = (u16*)(ws + (22ull << 20));       // 2 MB [1024][1024]
  u16* Qb = (u16*)(ws + (24ull << 20));        // 16 MB [B*H][2048][64]
  u16* Kb = (u16*)(ws + (40ull << 20));        // 16 MB
  u16* Vt = (u16*)(ws + (56ull << 20));        // 16 MB [1024][8192]

  convx<<<4096, 256, 0, stream>>>((const float4*)x, (u16x8*)Xb, 1048576);
  transpose_w<<<dim3(96, 32), 256, 0, stream>>>(wqkv, Wt, 1024, 3072);
  transpose_w<<<dim3(32, 32), 256, 0, stream>>>(wout, WoT, 1024, 1024);

  // Q,K: [8192,1024] x [1024,2048] -> scatter
  gemm_bt<1><<<dim3(16, 64), 256, 0, stream>>>(Xb, Wt, nullptr, 8192, 2048,
                                               1024, Qb, Kb);
  // V^T: Wv^T [1024,1024] x Xb^T -> Vt [1024][8192]
  gemm_bt<0><<<dim3(64, 8), 256, 0, stream>>>(Wt + (size_t)2048 * 1024, Xb, Vt,
                                              1024, 8192, 1024, nullptr, nullptr);
  // attention; writes bf16 attn output into Xb (dead after V-GEMM)
  attn_fwd<<<dim3(8, 64), 256, 0, stream>>>(Qb, Kb, Vt, Xb);
  // out = attn @ w_out : [8192,1024] x [1024,1024] -> fp32
  gemm_bt<2><<<dim3(8, 64), 256, 0, stream>>>(Xb, WoT, out, 8192, 1024, 1024,
                                              nullptr, nullptr);
}

// Round 4
// 246.147 us; speedup vs baseline: 2.3443x; 1.1744x over previous
//
#include <hip/hip_runtime.h>
#include <hip/hip_bf16.h>

typedef unsigned short u16;
typedef float f32x4 __attribute__((ext_vector_type(4)));
typedef __bf16 bf16x8 __attribute__((ext_vector_type(8)));
typedef u16 u16x8 __attribute__((ext_vector_type(8)));

__device__ __forceinline__ u16 f2bf(float f) {
  unsigned u = __builtin_bit_cast(unsigned, f);
  u = (u + 0x7fffu + ((u >> 16) & 1u)) >> 16;
  return (u16)u;
}

__device__ __forceinline__ void gload16(const void* g, void* l) {
  __builtin_amdgcn_global_load_lds(
      (const __attribute__((address_space(1))) unsigned*)g,
      (__attribute__((address_space(3))) unsigned*)l, 16, 0, 0);
}

// ---------------- convert x (fp32 -> bf16), 8 elems/thread ----------------
__global__ __launch_bounds__(256) void convx(const float4* __restrict__ x,
                                             u16x8* __restrict__ xb, int n) {
  int i = blockIdx.x * 256 + threadIdx.x;
  if (i >= n) return;
  float4 a = x[2 * i], b = x[2 * i + 1];
  u16x8 o;
  o[0] = f2bf(a.x); o[1] = f2bf(a.y); o[2] = f2bf(a.z); o[3] = f2bf(a.w);
  o[4] = f2bf(b.x); o[5] = f2bf(b.y); o[6] = f2bf(b.z); o[7] = f2bf(b.w);
  xb[i] = o;
}

// ------------- transpose weight fp32 [R][C] -> bf16 [C][R] ---------------
__global__ __launch_bounds__(256) void transpose_w(const float* __restrict__ w,
                                                   u16* __restrict__ wt,
                                                   int R, int C) {
  __shared__ float tile[32][33];
  int n0 = blockIdx.x * 32, k0 = blockIdx.y * 32;
  int tx = threadIdx.x & 31, ty = threadIdx.x >> 5;  // ty 0..7
#pragma unroll
  for (int j = 0; j < 32; j += 8)
    tile[ty + j][tx] = w[(size_t)(k0 + ty + j) * C + n0 + tx];
  __syncthreads();
#pragma unroll
  for (int j = 0; j < 32; j += 8)
    wt[(size_t)(n0 + ty + j) * R + k0 + tx] = f2bf(tile[tx][ty + j]);
}

// ---------------- GEMM: C[M][N] = A[M][K] * Bt[N][K]^T -------------------
// MODE 0: bf16 row-major C ; MODE 1: QK scatter (Q pre-scaled) ; MODE 2: fp32
template <int MODE>
__global__ __launch_bounds__(256) void gemm_bt(const u16* __restrict__ A,
                                               const u16* __restrict__ Bt,
                                               void* __restrict__ Cv,
                                               int M, int N, int K,
                                               u16* __restrict__ Qb,
                                               u16* __restrict__ Kb) {
  __shared__ alignas(16) u16 As[128 * 32];
  __shared__ alignas(16) u16 Bs[128 * 32];
  const int t = threadIdx.x;
  const int lane = t & 63, wid = t >> 6;
  const int wr = wid >> 1, wc = wid & 1;
  const int r = lane & 15, g = lane >> 4;
  const int m0 = blockIdx.y * 128, n0 = blockIdx.x * 128;

  f32x4 acc[4][4] = {};

  const int c0 = wid * 2;  // this wave's two 16-row chunks
  const u16* ga0 = A + (size_t)(m0 + c0 * 16 + (lane >> 2)) * K + (lane & 3) * 8;
  const u16* gb0 = Bt + (size_t)(n0 + c0 * 16 + (lane >> 2)) * K + (lane & 3) * 8;
  const u16* ga1 = ga0 + (size_t)16 * K;
  const u16* gb1 = gb0 + (size_t)16 * K;
  u16* lA0 = &As[c0 * 512];
  u16* lA1 = &As[c0 * 512 + 512];
  u16* lB0 = &Bs[c0 * 512];
  u16* lB1 = &Bs[c0 * 512 + 512];

  for (int k0 = 0; k0 < K; k0 += 32) {
    gload16(ga0 + k0, lA0);
    gload16(ga1 + k0, lA1);
    gload16(gb0 + k0, lB0);
    gload16(gb1 + k0, lB1);
    __syncthreads();
    bf16x8 af[4], bfm[4];
#pragma unroll
    for (int i = 0; i < 4; ++i)
      af[i] = *(const bf16x8*)&As[(wr * 64 + i * 16 + r) * 32 + g * 8];
#pragma unroll
    for (int i = 0; i < 4; ++i)
      bfm[i] = *(const bf16x8*)&Bs[(wc * 64 + i * 16 + r) * 32 + g * 8];
#pragma unroll
    for (int i = 0; i < 4; ++i)
#pragma unroll
      for (int j = 0; j < 4; ++j)
        acc[i][j] = __builtin_amdgcn_mfma_f32_16x16x32_bf16(af[i], bfm[j],
                                                            acc[i][j], 0, 0, 0);
    __syncthreads();
  }

#pragma unroll
  for (int i = 0; i < 4; ++i) {
    int row = m0 + wr * 64 + i * 16 + g * 4;
#pragma unroll
    for (int j = 0; j < 4; ++j) {
      int col = n0 + wc * 64 + j * 16 + r;
#pragma unroll
      for (int e = 0; e < 4; ++e) {
        float v = acc[i][j][e];
        int rr = row + e;
        if (MODE == 0) {
          ((u16*)Cv)[(size_t)rr * N + col] = f2bf(v);
        } else if (MODE == 2) {
          ((float*)Cv)[(size_t)rr * N + col] = v;
        } else {
          int which = col >> 10, hh = (col >> 6) & 15, dd = col & 63;
          int bb = rr >> 11, ss = rr & 2047;
          size_t idx = ((size_t)(bb * 16 + hh) * 2048 + ss) * 64 + dd;
          // Q pre-scaled by SCALE*log2(e) so attn softmax uses exp2 directly
          (which ? Kb : Qb)[idx] = f2bf(which ? v : v * 0.18033688011112042f);
        }
      }
    }
  }
}

// ---------------- flash attention, block-staged K/V, paired q-tiles -------
// Q,K: [B*H][2048][64] bf16 (Q pre-scaled) ; Vt: [1024][8192] bf16
// O: [8192][1024] bf16
// Block: 8 waves x 16 q-rows = 128 q-rows. KVB=64, K/V double-buffered LDS.
// Pairing: block handles q-tile (15-bx) then bx -> exactly 17 kv-tiles each.
// 512 thr x 512 blocks = 4096 waves = 4 waves/SIMD (2 blocks/CU by LDS 50KB).
__global__ __launch_bounds__(512, 4) void attn_fwd(const u16* __restrict__ Q,
                                                   const u16* __restrict__ Kc,
                                                   const u16* __restrict__ Vt,
                                                   u16* __restrict__ O) {
  __shared__ alignas(16) u16 Ks[2][64][64];
  __shared__ alignas(16) u16 Vs[2][64][64];
  __shared__ alignas(16) u16 Ps[8][16][72];
  const int lane = threadIdx.x & 63, wid = threadIdx.x >> 6;  // wid 0..7
  const int r = lane & 15, g = lane >> 4;
  const int bh = blockIdx.y, b = bh >> 4, h = bh & 15;

  const u16* Kp = Kc + (size_t)bh * 2048 * 64;
  const u16* Vp = Vt + (size_t)(h * 64) * 8192 + (size_t)b * 2048;
  u16* pw = &Ps[wid][0][0];

  const int srow = lane >> 3;                // 0..7
  const int scol = ((lane & 7) ^ srow) * 8;  // pre-swizzled source col (elems)

  for (int pass = 0; pass < 2; ++pass) {
    const int qb = pass ? (int)blockIdx.x : 15 - (int)blockIdx.x;
    const int qw = qb * 128 + wid * 16;  // this wave's 16 q-rows
    const int nkv = 2 * (qb + 1);
    const u16* Qp = Q + ((size_t)bh * 2048 + qw) * 64;

    bf16x8 qf[2];
    qf[0] = *(const bf16x8*)(Qp + (size_t)r * 64 + g * 8);
    qf[1] = *(const bf16x8*)(Qp + (size_t)r * 64 + 32 + g * 8);

    f32x4 o[4] = {};
    float m[4] = {-1e30f, -1e30f, -1e30f, -1e30f};
    float l[4] = {0.f, 0.f, 0.f, 0.f};

    __syncthreads();  // previous pass done with all LDS buffers

    // stage tile 0 (each wave: 8 rows of K, 8 rows of V; 1 gload each)
    gload16(Kp + (size_t)(wid * 8 + srow) * 64 + scol, &Ks[0][wid * 8][0]);
    gload16(Vp + (size_t)(wid * 8 + srow) * 8192 + scol, &Vs[0][wid * 8][0]);

    int cur = 0;
    for (int t = 0; t < nkv; ++t, cur ^= 1) {
      __syncthreads();  // tile t resident; all waves done with buffer cur^1
      if (t + 1 < nkv) {  // async prefetch of tile t+1
        const int kn = (t + 1) * 64;
        gload16(Kp + (size_t)(kn + wid * 8 + srow) * 64 + scol, &Ks[cur ^ 1][wid * 8][0]);
        gload16(Vp + (size_t)(wid * 8 + srow) * 8192 + kn + scol, &Vs[cur ^ 1][wid * 8][0]);
      }
      const int kv0 = t * 64;
      if (kv0 > qw + 15) continue;  // wave-uniform: fully masked

      // ---- QK^T: 16q x 64kv, K=64 (scores pre-scaled, log2 domain) ----
      f32x4 s[4];
#pragma unroll
      for (int tt = 0; tt < 4; ++tt) {
        bf16x8 k0 = *(const bf16x8*)&Ks[cur][tt * 16 + r][((0 + g) ^ (r & 7)) * 8];
        bf16x8 k1 = *(const bf16x8*)&Ks[cur][tt * 16 + r][((4 + g) ^ (r & 7)) * 8];
        f32x4 z = {};
        z = __builtin_amdgcn_mfma_f32_16x16x32_bf16(qf[0], k0, z, 0, 0, 0);
        z = __builtin_amdgcn_mfma_f32_16x16x32_bf16(qf[1], k1, z, 0, 0, 0);
        s[tt] = z;
      }
      if (kv0 + 63 > qw) {  // diagonal-crossing tiles: causal mask
#pragma unroll
        for (int tt = 0; tt < 4; ++tt) {
          int col = kv0 + tt * 16 + r;
#pragma unroll
          for (int e = 0; e < 4; ++e)
            if (col > qw + g * 4 + e) s[tt][e] = -1e30f;
        }
      }

      // ---- online softmax (base-2 domain; no per-element multiply) ----
      float sf[4];
#pragma unroll
      for (int e = 0; e < 4; ++e) {
        float pm = fmaxf(fmaxf(s[0][e], s[1][e]), fmaxf(s[2][e], s[3][e]));
        pm = fmaxf(pm, __shfl_xor(pm, 1));
        pm = fmaxf(pm, __shfl_xor(pm, 2));
        pm = fmaxf(pm, __shfl_xor(pm, 4));
        pm = fmaxf(pm, __shfl_xor(pm, 8));
        float mn = fmaxf(m[e], pm);
        sf[e] = exp2f(m[e] - mn);
        m[e] = mn;
      }
      float rs[4] = {};
#pragma unroll
      for (int tt = 0; tt < 4; ++tt)
#pragma unroll
        for (int e = 0; e < 4; ++e) {
          float p = exp2f(s[tt][e] - m[e]);
          rs[e] += p;
          pw[(g * 4 + e) * 72 + tt * 16 + r] = f2bf(p);
        }
#pragma unroll
      for (int e = 0; e < 4; ++e) {
        float t2 = rs[e];
        t2 += __shfl_xor(t2, 1);
        t2 += __shfl_xor(t2, 2);
        t2 += __shfl_xor(t2, 4);
        t2 += __shfl_xor(t2, 8);
        l[e] = l[e] * sf[e] + t2;
#pragma unroll
        for (int dt = 0; dt < 4; ++dt) o[dt][e] *= sf[e];
      }

      // ---- PV: O[16q][64d] += P[16q][64kv] * V[64kv][64d] ----
      bf16x8 pf0 = *(const bf16x8*)&pw[r * 72 + g * 8];
      bf16x8 pf1 = *(const bf16x8*)&pw[r * 72 + 32 + g * 8];
#pragma unroll
      for (int dt = 0; dt < 4; ++dt) {
        bf16x8 v0 = *(const bf16x8*)&Vs[cur][dt * 16 + r][((0 + g) ^ (r & 7)) * 8];
        bf16x8 v1 = *(const bf16x8*)&Vs[cur][dt * 16 + r][((4 + g) ^ (r & 7)) * 8];
        o[dt] = __builtin_amdgcn_mfma_f32_16x16x32_bf16(pf0, v0, o[dt], 0, 0, 0);
        o[dt] = __builtin_amdgcn_mfma_f32_16x16x32_bf16(pf1, v1, o[dt], 0, 0, 0);
      }
    }

#pragma unroll
    for (int e = 0; e < 4; ++e) {
      float inv = 1.f / l[e];
#pragma unroll
      for (int dt = 0; dt < 4; ++dt)
        O[((size_t)b * 2048 + qw + g * 4 + e) * 1024 + h * 64 + dt * 16 + r] =
            f2bf(o[dt][e] * inv);
    }
  }
}

extern "C" void kernel_launch(void* const* d_in, const int* in_sizes, int n_in,
                              void* d_out, int out_size, void* d_ws,
                              size_t ws_size, hipStream_t stream) {
  const float* x = (const float*)d_in[0];
  const float* wqkv = (const float*)d_in[1];
  const float* wout = (const float*)d_in[2];
  float* out = (float*)d_out;
  char* ws = (char*)d_ws;

  // workspace layout (bytes)
  u16* Xb = (u16*)ws;                          // 16 MB [8192][1024] (later: attn out)
  u16* Wt = (u16*)(ws + (16ull << 20));        // 6 MB [3072][1024]
  u16* WoT = (u16*)(ws + (22ull << 20));       // 2 MB [1024][1024]
  u16* Qb = (u16*)(ws + (24ull << 20));        // 16 MB [B*H][2048][64]
  u16* Kb = (u16*)(ws + (40ull << 20));        // 16 MB
  u16* Vt = (u16*)(ws + (56ull << 20));        // 16 MB [1024][8192]

  convx<<<4096, 256, 0, stream>>>((const float4*)x, (u16x8*)Xb, 1048576);
  transpose_w<<<dim3(96, 32), 256, 0, stream>>>(wqkv, Wt, 1024, 3072);
  transpose_w<<<dim3(32, 32), 256, 0, stream>>>(wout, WoT, 1024, 1024);

  // Q,K: [8192,1024] x [1024,2048] -> scatter (Q pre-scaled)
  gemm_bt<1><<<dim3(16, 64), 256, 0, stream>>>(Xb, Wt, nullptr, 8192, 2048,
                                               1024, Qb, Kb);
  // V^T: Wv^T [1024,1024] x Xb^T -> Vt [1024][8192]
  gemm_bt<0><<<dim3(64, 8), 256, 0, stream>>>(Wt + (size_t)2048 * 1024, Xb, Vt,
                                              1024, 8192, 1024, nullptr, nullptr);
  // attention; writes bf16 attn output into Xb (dead after V-GEMM)
  attn_fwd<<<dim3(8, 64), 512, 0, stream>>>(Qb, Kb, Vt, Xb);
  // out = attn @ w_out : [8192,1024] x [1024,1024] -> fp32
  gemm_bt<2><<<dim3(8, 64), 256, 0, stream>>>(Xb, WoT, out, 8192, 1024, 1024,
                                              nullptr, nullptr);
}

// Round 5
// 211.614 us; speedup vs baseline: 2.7269x; 1.1632x over previous
//
#include <hip/hip_runtime.h>
#include <hip/hip_bf16.h>

typedef unsigned short u16;
typedef float f32x4 __attribute__((ext_vector_type(4)));
typedef __bf16 bf16x8 __attribute__((ext_vector_type(8)));
typedef u16 u16x8 __attribute__((ext_vector_type(8)));
typedef u16 u16x4 __attribute__((ext_vector_type(4)));

__device__ __forceinline__ u16 f2bf(float f) {
  unsigned u = __builtin_bit_cast(unsigned, f);
  u = (u + 0x7fffu + ((u >> 16) & 1u)) >> 16;
  return (u16)u;
}

__device__ __forceinline__ unsigned pack2bf(float a, float b) {
  return (unsigned)f2bf(a) | ((unsigned)f2bf(b) << 16);
}

__device__ __forceinline__ void gload16(const void* g, void* l) {
  __builtin_amdgcn_global_load_lds(
      (const __attribute__((address_space(1))) unsigned*)g,
      (__attribute__((address_space(3))) unsigned*)l, 16, 0, 0);
}

// ---------------- convert x (fp32 -> bf16), 8 elems/thread ----------------
__global__ __launch_bounds__(256) void convx(const float4* __restrict__ x,
                                             u16x8* __restrict__ xb, int n) {
  int i = blockIdx.x * 256 + threadIdx.x;
  if (i >= n) return;
  float4 a = x[2 * i], b = x[2 * i + 1];
  u16x8 o;
  o[0] = f2bf(a.x); o[1] = f2bf(a.y); o[2] = f2bf(a.z); o[3] = f2bf(a.w);
  o[4] = f2bf(b.x); o[5] = f2bf(b.y); o[6] = f2bf(b.z); o[7] = f2bf(b.w);
  xb[i] = o;
}

// ------------- transpose weight fp32 [R][C] -> bf16 [C][R] ---------------
__global__ __launch_bounds__(256) void transpose_w(const float* __restrict__ w,
                                                   u16* __restrict__ wt,
                                                   int R, int C) {
  __shared__ float tile[32][33];
  int n0 = blockIdx.x * 32, k0 = blockIdx.y * 32;
  int tx = threadIdx.x & 31, ty = threadIdx.x >> 5;  // ty 0..7
#pragma unroll
  for (int j = 0; j < 32; j += 8)
    tile[ty + j][tx] = w[(size_t)(k0 + ty + j) * C + n0 + tx];
  __syncthreads();
#pragma unroll
  for (int j = 0; j < 32; j += 8)
    wt[(size_t)(n0 + ty + j) * R + k0 + tx] = f2bf(tile[tx][ty + j]);
}

// ---------------- GEMM: C[M][N] = A[M][K] * Bt[N][K]^T -------------------
// MODE 0: bf16 row-major C ; MODE 1: QK scatter (Q pre-scaled) ; MODE 2: fp32
template <int MODE>
__global__ __launch_bounds__(256) void gemm_bt(const u16* __restrict__ A,
                                               const u16* __restrict__ Bt,
                                               void* __restrict__ Cv,
                                               int M, int N, int K,
                                               u16* __restrict__ Qb,
                                               u16* __restrict__ Kb) {
  __shared__ alignas(16) u16 As[128 * 32];
  __shared__ alignas(16) u16 Bs[128 * 32];
  const int t = threadIdx.x;
  const int lane = t & 63, wid = t >> 6;
  const int wr = wid >> 1, wc = wid & 1;
  const int r = lane & 15, g = lane >> 4;
  const int m0 = blockIdx.y * 128, n0 = blockIdx.x * 128;

  f32x4 acc[4][4] = {};

  const int c0 = wid * 2;  // this wave's two 16-row chunks
  const u16* ga0 = A + (size_t)(m0 + c0 * 16 + (lane >> 2)) * K + (lane & 3) * 8;
  const u16* gb0 = Bt + (size_t)(n0 + c0 * 16 + (lane >> 2)) * K + (lane & 3) * 8;
  const u16* ga1 = ga0 + (size_t)16 * K;
  const u16* gb1 = gb0 + (size_t)16 * K;
  u16* lA0 = &As[c0 * 512];
  u16* lA1 = &As[c0 * 512 + 512];
  u16* lB0 = &Bs[c0 * 512];
  u16* lB1 = &Bs[c0 * 512 + 512];

  for (int k0 = 0; k0 < K; k0 += 32) {
    gload16(ga0 + k0, lA0);
    gload16(ga1 + k0, lA1);
    gload16(gb0 + k0, lB0);
    gload16(gb1 + k0, lB1);
    __syncthreads();
    bf16x8 af[4], bfm[4];
#pragma unroll
    for (int i = 0; i < 4; ++i)
      af[i] = *(const bf16x8*)&As[(wr * 64 + i * 16 + r) * 32 + g * 8];
#pragma unroll
    for (int i = 0; i < 4; ++i)
      bfm[i] = *(const bf16x8*)&Bs[(wc * 64 + i * 16 + r) * 32 + g * 8];
#pragma unroll
    for (int i = 0; i < 4; ++i)
#pragma unroll
      for (int j = 0; j < 4; ++j)
        acc[i][j] = __builtin_amdgcn_mfma_f32_16x16x32_bf16(af[i], bfm[j],
                                                            acc[i][j], 0, 0, 0);
    __syncthreads();
  }

#pragma unroll
  for (int i = 0; i < 4; ++i) {
    int row = m0 + wr * 64 + i * 16 + g * 4;
#pragma unroll
    for (int j = 0; j < 4; ++j) {
      int col = n0 + wc * 64 + j * 16 + r;
#pragma unroll
      for (int e = 0; e < 4; ++e) {
        float v = acc[i][j][e];
        int rr = row + e;
        if (MODE == 0) {
          ((u16*)Cv)[(size_t)rr * N + col] = f2bf(v);
        } else if (MODE == 2) {
          ((float*)Cv)[(size_t)rr * N + col] = v;
        } else {
          int which = col >> 10, hh = (col >> 6) & 15, dd = col & 63;
          int bb = rr >> 11, ss = rr & 2047;
          size_t idx = ((size_t)(bb * 16 + hh) * 2048 + ss) * 64 + dd;
          // Q pre-scaled by SCALE*log2(e) so attn softmax uses exp2 directly
          (which ? Kb : Qb)[idx] = f2bf(which ? v : v * 0.18033688011112042f);
        }
      }
    }
  }
}

// ---------------- flash attention, swapped QK^T (S^T), one q per lane -----
// Q,K: [B*H][2048][64] bf16 (Q pre-scaled) ; Vt: [1024][8192] bf16
// O: [8192][1024] bf16
// Block: 8 waves x 16 q-rows = 128 q-rows, ONE q-tile per block.
// Grid (64 bh, 16 qb) with qb=15-by: heaviest tiles dispatch first.
// Swapped mfma(K,Q) -> lane owns one q-row: in-lane softmax, 4 shfls/tile.
// LDS 50KB -> 3 blocks/CU (24 waves/CU).
__global__ __launch_bounds__(512, 6) void attn_fwd(const u16* __restrict__ Q,
                                                   const u16* __restrict__ Kc,
                                                   const u16* __restrict__ Vt,
                                                   u16* __restrict__ O) {
  __shared__ alignas(16) u16 Ks[2][64][64];
  __shared__ alignas(16) u16 Vs[2][64][64];  // actually V^T: [d][kv]
  __shared__ alignas(16) u16 Ps[8][16][72];  // P[q][kv] per wave
  const int lane = threadIdx.x & 63, wid = threadIdx.x >> 6;  // wid 0..7
  const int r = lane & 15, g = lane >> 4;
  const int bh = blockIdx.x, b = bh >> 4, h = bh & 15;
  const int qb = 15 - (int)blockIdx.y;  // heavy first
  const int qw = qb * 128 + wid * 16;   // this wave's 16 q-rows
  const int nkv = 2 * (qb + 1);

  const u16* Kp = Kc + (size_t)bh * 2048 * 64;
  const u16* Vp = Vt + (size_t)(h * 64) * 8192 + (size_t)b * 2048;
  const u16* Qp = Q + ((size_t)bh * 2048 + qw) * 64;
  u16* pw = &Ps[wid][0][0];

  const int srow = lane >> 3;                // 0..7
  const int scol = ((lane & 7) ^ srow) * 8;  // pre-swizzled source col (elems)

  // Q fragments (serve as MFMA B-operand in swapped form; same layout)
  bf16x8 qf[2];
  qf[0] = *(const bf16x8*)(Qp + (size_t)r * 64 + g * 8);
  qf[1] = *(const bf16x8*)(Qp + (size_t)r * 64 + 32 + g * 8);

  f32x4 o[4] = {};           // O^T frag: d = dt*16+g*4+e, q = r
  float m = -1e30f, l = 0.f; // per-lane scalars (one q-row per lane)

  // stage tile 0 (each wave: 8 rows of K, 8 rows of V^T)
  gload16(Kp + (size_t)(wid * 8 + srow) * 64 + scol, &Ks[0][wid * 8][0]);
  gload16(Vp + (size_t)(wid * 8 + srow) * 8192 + scol, &Vs[0][wid * 8][0]);

  int cur = 0;
  for (int t = 0; t < nkv; ++t, cur ^= 1) {
    __syncthreads();  // tile t resident; all waves done with buffer cur^1
    if (t + 1 < nkv) {  // async prefetch of tile t+1
      const int kn = (t + 1) * 64;
      gload16(Kp + (size_t)(kn + wid * 8 + srow) * 64 + scol, &Ks[cur ^ 1][wid * 8][0]);
      gload16(Vp + (size_t)(wid * 8 + srow) * 8192 + kn + scol, &Vs[cur ^ 1][wid * 8][0]);
    }
    const int kv0 = t * 64;
    if (kv0 > qw + 15) continue;  // wave-uniform: fully masked

    // ---- swapped QK^T: S^T[kv][q], lane holds kv=tt*16+g*4+e for q=r ----
    f32x4 s[4];
#pragma unroll
    for (int tt = 0; tt < 4; ++tt) {
      bf16x8 k0 = *(const bf16x8*)&Ks[cur][tt * 16 + r][((0 + g) ^ (r & 7)) * 8];
      bf16x8 k1 = *(const bf16x8*)&Ks[cur][tt * 16 + r][((4 + g) ^ (r & 7)) * 8];
      f32x4 z = {};
      z = __builtin_amdgcn_mfma_f32_16x16x32_bf16(k0, qf[0], z, 0, 0, 0);
      z = __builtin_amdgcn_mfma_f32_16x16x32_bf16(k1, qf[1], z, 0, 0, 0);
      s[tt] = z;
    }
    if (kv0 + 63 > qw) {  // diagonal-crossing tiles: causal mask (kv > q)
#pragma unroll
      for (int tt = 0; tt < 4; ++tt) {
        int kvb = kv0 + tt * 16 + g * 4;
#pragma unroll
        for (int e = 0; e < 4; ++e)
          if (kvb + e > qw + r) s[tt][e] = -1e30f;
      }
    }

    // ---- online softmax: in-lane tree + 2 shfls (groups differ in g) ----
    f32x4 t4;
#pragma unroll
    for (int e = 0; e < 4; ++e)
      t4[e] = fmaxf(fmaxf(s[0][e], s[1][e]), fmaxf(s[2][e], s[3][e]));
    float pm = fmaxf(fmaxf(t4[0], t4[1]), fmaxf(t4[2], t4[3]));
    pm = fmaxf(pm, __shfl_xor(pm, 16));
    pm = fmaxf(pm, __shfl_xor(pm, 32));
    float mn = fmaxf(m, pm);
    float sf = exp2f(m - mn);
    m = mn;

    f32x4 p[4];
#pragma unroll
    for (int tt = 0; tt < 4; ++tt)
#pragma unroll
      for (int e = 0; e < 4; ++e) p[tt][e] = exp2f(s[tt][e] - m);
    // pack pairs and store P[q=r][kv] (8 x ds_write_b32)
#pragma unroll
    for (int tt = 0; tt < 4; ++tt) {
      *(unsigned*)&pw[r * 72 + tt * 16 + g * 4] = pack2bf(p[tt][0], p[tt][1]);
      *(unsigned*)&pw[r * 72 + tt * 16 + g * 4 + 2] = pack2bf(p[tt][2], p[tt][3]);
    }
    f32x4 s4;
#pragma unroll
    for (int e = 0; e < 4; ++e)
      s4[e] = (p[0][e] + p[1][e]) + (p[2][e] + p[3][e]);
    float rs = (s4[0] + s4[1]) + (s4[2] + s4[3]);
    rs += __shfl_xor(rs, 16);
    rs += __shfl_xor(rs, 32);
    l = l * sf + rs;
#pragma unroll
    for (int dt = 0; dt < 4; ++dt)
#pragma unroll
      for (int e = 0; e < 4; ++e) o[dt][e] *= sf;

    // ---- PV: O^T[d][q] += V^T[d][kv] * P^T[kv][q] ----
    bf16x8 pB0 = *(const bf16x8*)&pw[r * 72 + g * 8];
    bf16x8 pB1 = *(const bf16x8*)&pw[r * 72 + 32 + g * 8];
#pragma unroll
    for (int dt = 0; dt < 4; ++dt) {
      bf16x8 v0 = *(const bf16x8*)&Vs[cur][dt * 16 + r][((0 + g) ^ (r & 7)) * 8];
      bf16x8 v1 = *(const bf16x8*)&Vs[cur][dt * 16 + r][((4 + g) ^ (r & 7)) * 8];
      o[dt] = __builtin_amdgcn_mfma_f32_16x16x32_bf16(v0, pB0, o[dt], 0, 0, 0);
      o[dt] = __builtin_amdgcn_mfma_f32_16x16x32_bf16(v1, pB1, o[dt], 0, 0, 0);
    }
  }

  // ---- epilogue: lane holds O^T[d=dt*16+g*4+e][q=r]; write O[s][h*64+d] ----
  float inv = 1.f / l;
  size_t rowbase = ((size_t)b * 2048 + qw + r) * 1024 + h * 64;
#pragma unroll
  for (int dt = 0; dt < 4; ++dt) {
    u16x4 ov;
#pragma unroll
    for (int e = 0; e < 4; ++e) ov[e] = f2bf(o[dt][e] * inv);
    *(u16x4*)&O[rowbase + dt * 16 + g * 4] = ov;
  }
}

extern "C" void kernel_launch(void* const* d_in, const int* in_sizes, int n_in,
                              void* d_out, int out_size, void* d_ws,
                              size_t ws_size, hipStream_t stream) {
  const float* x = (const float*)d_in[0];
  const float* wqkv = (const float*)d_in[1];
  const float* wout = (const float*)d_in[2];
  float* out = (float*)d_out;
  char* ws = (char*)d_ws;

  // workspace layout (bytes)
  u16* Xb = (u16*)ws;                          // 16 MB [8192][1024] (later: attn out)
  u16* Wt = (u16*)(ws + (16ull << 20));        // 6 MB [3072][1024]
  u16* WoT = (u16*)(ws + (22ull << 20));       // 2 MB [1024][1024]
  u16* Qb = (u16*)(ws + (24ull << 20));        // 16 MB [B*H][2048][64]
  u16* Kb = (u16*)(ws + (40ull << 20));        // 16 MB
  u16* Vt = (u16*)(ws + (56ull << 20));        // 16 MB [1024][8192]

  convx<<<4096, 256, 0, stream>>>((const float4*)x, (u16x8*)Xb, 1048576);
  transpose_w<<<dim3(96, 32), 256, 0, stream>>>(wqkv, Wt, 1024, 3072);
  transpose_w<<<dim3(32, 32), 256, 0, stream>>>(wout, WoT, 1024, 1024);

  // Q,K: [8192,1024] x [1024,2048] -> scatter (Q pre-scaled)
  gemm_bt<1><<<dim3(16, 64), 256, 0, stream>>>(Xb, Wt, nullptr, 8192, 2048,
                                               1024, Qb, Kb);
  // V^T: Wv^T [1024,1024] x Xb^T -> Vt [1024][8192]
  gemm_bt<0><<<dim3(64, 8), 256, 0, stream>>>(Wt + (size_t)2048 * 1024, Xb, Vt,
                                              1024, 8192, 1024, nullptr, nullptr);
  // attention; writes bf16 attn output into Xb (dead after V-GEMM)
  attn_fwd<<<dim3(64, 16), 512, 0, stream>>>(Qb, Kb, Vt, Xb);
  // out = attn @ w_out : [8192,1024] x [1024,1024] -> fp32
  gemm_bt<2><<<dim3(8, 64), 256, 0, stream>>>(Xb, WoT, out, 8192, 1024, 1024,
                                              nullptr, nullptr);
}

// Round 6
// 203.168 us; speedup vs baseline: 2.8403x; 1.0416x over previous
//
#include <hip/hip_runtime.h>
#include <hip/hip_bf16.h>

typedef unsigned short u16;
typedef float f32x4 __attribute__((ext_vector_type(4)));
typedef __bf16 bf16x8 __attribute__((ext_vector_type(8)));
typedef u16 u16x8 __attribute__((ext_vector_type(8)));
typedef u16 u16x4 __attribute__((ext_vector_type(4)));
typedef unsigned u32x2 __attribute__((ext_vector_type(2)));

__device__ __forceinline__ u16 f2bf(float f) {
  unsigned u = __builtin_bit_cast(unsigned, f);
  u = (u + 0x7fffu + ((u >> 16) & 1u)) >> 16;
  return (u16)u;
}

// packed f32 pair -> bf16 pair (RNE), single instruction on gfx950
__device__ __forceinline__ unsigned cvtpk(float lo, float hi) {
  unsigned r;
  asm("v_cvt_pk_bf16_f32 %0, %1, %2" : "=v"(r) : "v"(lo), "v"(hi));
  return r;
}

__device__ __forceinline__ void gload16(const void* g, void* l) {
  __builtin_amdgcn_global_load_lds(
      (const __attribute__((address_space(1))) unsigned*)g,
      (__attribute__((address_space(3))) unsigned*)l, 16, 0, 0);
}

// ---------------- convert x (fp32 -> bf16), 8 elems/thread ----------------
__global__ __launch_bounds__(256) void convx(const float4* __restrict__ x,
                                             u16x8* __restrict__ xb, int n) {
  int i = blockIdx.x * 256 + threadIdx.x;
  if (i >= n) return;
  float4 a = x[2 * i], b = x[2 * i + 1];
  u16x8 o;
  o[0] = f2bf(a.x); o[1] = f2bf(a.y); o[2] = f2bf(a.z); o[3] = f2bf(a.w);
  o[4] = f2bf(b.x); o[5] = f2bf(b.y); o[6] = f2bf(b.z); o[7] = f2bf(b.w);
  xb[i] = o;
}

// ------------- transpose weight fp32 [R][C] -> bf16 [C][R] ---------------
__global__ __launch_bounds__(256) void transpose_w(const float* __restrict__ w,
                                                   u16* __restrict__ wt,
                                                   int R, int C) {
  __shared__ float tile[32][33];
  int n0 = blockIdx.x * 32, k0 = blockIdx.y * 32;
  int tx = threadIdx.x & 31, ty = threadIdx.x >> 5;  // ty 0..7
#pragma unroll
  for (int j = 0; j < 32; j += 8)
    tile[ty + j][tx] = w[(size_t)(k0 + ty + j) * C + n0 + tx];
  __syncthreads();
#pragma unroll
  for (int j = 0; j < 32; j += 8)
    wt[(size_t)(n0 + ty + j) * R + k0 + tx] = f2bf(tile[tx][ty + j]);
}

// ---------------- GEMM: C[M][N] = A[M][K] * Bt[N][K]^T -------------------
// MODE 0: bf16 row-major C ; MODE 1: QK scatter (Q pre-scaled) ; MODE 2: fp32
template <int MODE>
__global__ __launch_bounds__(256) void gemm_bt(const u16* __restrict__ A,
                                               const u16* __restrict__ Bt,
                                               void* __restrict__ Cv,
                                               int M, int N, int K,
                                               u16* __restrict__ Qb,
                                               u16* __restrict__ Kb) {
  __shared__ alignas(16) u16 As[128 * 32];
  __shared__ alignas(16) u16 Bs[128 * 32];
  const int t = threadIdx.x;
  const int lane = t & 63, wid = t >> 6;
  const int wr = wid >> 1, wc = wid & 1;
  const int r = lane & 15, g = lane >> 4;
  const int m0 = blockIdx.y * 128, n0 = blockIdx.x * 128;

  f32x4 acc[4][4] = {};

  const int c0 = wid * 2;  // this wave's two 16-row chunks
  const u16* ga0 = A + (size_t)(m0 + c0 * 16 + (lane >> 2)) * K + (lane & 3) * 8;
  const u16* gb0 = Bt + (size_t)(n0 + c0 * 16 + (lane >> 2)) * K + (lane & 3) * 8;
  const u16* ga1 = ga0 + (size_t)16 * K;
  const u16* gb1 = gb0 + (size_t)16 * K;
  u16* lA0 = &As[c0 * 512];
  u16* lA1 = &As[c0 * 512 + 512];
  u16* lB0 = &Bs[c0 * 512];
  u16* lB1 = &Bs[c0 * 512 + 512];

  for (int k0 = 0; k0 < K; k0 += 32) {
    gload16(ga0 + k0, lA0);
    gload16(ga1 + k0, lA1);
    gload16(gb0 + k0, lB0);
    gload16(gb1 + k0, lB1);
    __syncthreads();
    bf16x8 af[4], bfm[4];
#pragma unroll
    for (int i = 0; i < 4; ++i)
      af[i] = *(const bf16x8*)&As[(wr * 64 + i * 16 + r) * 32 + g * 8];
#pragma unroll
    for (int i = 0; i < 4; ++i)
      bfm[i] = *(const bf16x8*)&Bs[(wc * 64 + i * 16 + r) * 32 + g * 8];
#pragma unroll
    for (int i = 0; i < 4; ++i)
#pragma unroll
      for (int j = 0; j < 4; ++j)
        acc[i][j] = __builtin_amdgcn_mfma_f32_16x16x32_bf16(af[i], bfm[j],
                                                            acc[i][j], 0, 0, 0);
    __syncthreads();
  }

#pragma unroll
  for (int i = 0; i < 4; ++i) {
    int row = m0 + wr * 64 + i * 16 + g * 4;
#pragma unroll
    for (int j = 0; j < 4; ++j) {
      int col = n0 + wc * 64 + j * 16 + r;
#pragma unroll
      for (int e = 0; e < 4; ++e) {
        float v = acc[i][j][e];
        int rr = row + e;
        if (MODE == 0) {
          ((u16*)Cv)[(size_t)rr * N + col] = f2bf(v);
        } else if (MODE == 2) {
          ((float*)Cv)[(size_t)rr * N + col] = v;
        } else {
          int which = col >> 10, hh = (col >> 6) & 15, dd = col & 63;
          int bb = rr >> 11, ss = rr & 2047;
          size_t idx = ((size_t)(bb * 16 + hh) * 2048 + ss) * 64 + dd;
          // Q pre-scaled by SCALE*log2(e) so attn softmax uses exp2 directly
          (which ? Kb : Qb)[idx] = f2bf(which ? v : v * 0.18033688011112042f);
        }
      }
    }
  }
}

// ---------------- flash attention, swapped QK^T (S^T), one q per lane -----
// Q,K: [B*H][2048][64] bf16 (Q pre-scaled) ; Vt: [1024][8192] bf16
// O: [8192][1024] bf16
// Block: 8 waves x 16 q-rows = 128 q-rows, ONE q-tile per block.
// Grid (64 bh, 16 qb) with qb=15-by: heaviest tiles dispatch first.
// Swapped mfma(K,Q) -> lane owns one q-row: in-lane softmax, 4 shfls/tile.
// cvt_pk P-pack + defer-max rescale (THR=8 in log2 domain).
__global__ __launch_bounds__(512, 6) void attn_fwd(const u16* __restrict__ Q,
                                                   const u16* __restrict__ Kc,
                                                   const u16* __restrict__ Vt,
                                                   u16* __restrict__ O) {
  __shared__ alignas(16) u16 Ks[2][64][64];
  __shared__ alignas(16) u16 Vs[2][64][64];  // actually V^T: [d][kv]
  __shared__ alignas(16) u16 Ps[8][16][72];  // P[q][kv] per wave
  const int lane = threadIdx.x & 63, wid = threadIdx.x >> 6;  // wid 0..7
  const int r = lane & 15, g = lane >> 4;
  const int bh = blockIdx.x, b = bh >> 4, h = bh & 15;
  const int qb = 15 - (int)blockIdx.y;  // heavy first
  const int qw = qb * 128 + wid * 16;   // this wave's 16 q-rows
  const int nkv = 2 * (qb + 1);

  const u16* Kp = Kc + (size_t)bh * 2048 * 64;
  const u16* Vp = Vt + (size_t)(h * 64) * 8192 + (size_t)b * 2048;
  const u16* Qp = Q + ((size_t)bh * 2048 + qw) * 64;
  u16* pw = &Ps[wid][0][0];

  const int srow = lane >> 3;                // 0..7
  const int scol = ((lane & 7) ^ srow) * 8;  // pre-swizzled source col (elems)

  // Q fragments (serve as MFMA B-operand in swapped form; same layout)
  bf16x8 qf[2];
  qf[0] = *(const bf16x8*)(Qp + (size_t)r * 64 + g * 8);
  qf[1] = *(const bf16x8*)(Qp + (size_t)r * 64 + 32 + g * 8);

  f32x4 o[4] = {};           // O^T frag: d = dt*16+g*4+e, q = r
  float m = -1e30f, l = 0.f; // per-lane scalars (one q-row per lane)

  // stage tile 0 (each wave: 8 rows of K, 8 rows of V^T)
  gload16(Kp + (size_t)(wid * 8 + srow) * 64 + scol, &Ks[0][wid * 8][0]);
  gload16(Vp + (size_t)(wid * 8 + srow) * 8192 + scol, &Vs[0][wid * 8][0]);

  int cur = 0;
  for (int t = 0; t < nkv; ++t, cur ^= 1) {
    __syncthreads();  // tile t resident; all waves done with buffer cur^1
    if (t + 1 < nkv) {  // async prefetch of tile t+1
      const int kn = (t + 1) * 64;
      gload16(Kp + (size_t)(kn + wid * 8 + srow) * 64 + scol, &Ks[cur ^ 1][wid * 8][0]);
      gload16(Vp + (size_t)(wid * 8 + srow) * 8192 + kn + scol, &Vs[cur ^ 1][wid * 8][0]);
    }
    const int kv0 = t * 64;
    if (kv0 > qw + 15) continue;  // wave-uniform: fully masked

    // ---- swapped QK^T: S^T[kv][q], lane holds kv=tt*16+g*4+e for q=r ----
    f32x4 s[4];
#pragma unroll
    for (int tt = 0; tt < 4; ++tt) {
      bf16x8 k0 = *(const bf16x8*)&Ks[cur][tt * 16 + r][((0 + g) ^ (r & 7)) * 8];
      bf16x8 k1 = *(const bf16x8*)&Ks[cur][tt * 16 + r][((4 + g) ^ (r & 7)) * 8];
      f32x4 z = {};
      z = __builtin_amdgcn_mfma_f32_16x16x32_bf16(k0, qf[0], z, 0, 0, 0);
      z = __builtin_amdgcn_mfma_f32_16x16x32_bf16(k1, qf[1], z, 0, 0, 0);
      s[tt] = z;
    }
    if (kv0 + 63 > qw) {  // diagonal-crossing tiles: causal mask (kv > q)
#pragma unroll
      for (int tt = 0; tt < 4; ++tt) {
        int kvb = kv0 + tt * 16 + g * 4;
#pragma unroll
        for (int e = 0; e < 4; ++e)
          if (kvb + e > qw + r) s[tt][e] = -1e30f;
      }
    }

    // ---- online softmax: in-lane tree + 2 shfls; defer-max (THR=8) ----
    f32x4 t4;
#pragma unroll
    for (int e = 0; e < 4; ++e)
      t4[e] = fmaxf(fmaxf(s[0][e], s[1][e]), fmaxf(s[2][e], s[3][e]));
    float pm = fmaxf(fmaxf(t4[0], t4[1]), fmaxf(t4[2], t4[3]));
    pm = fmaxf(pm, __shfl_xor(pm, 16));
    pm = fmaxf(pm, __shfl_xor(pm, 32));
    if (__any(pm > m + 8.f)) {  // rescale only on significant max growth
      float mn = fmaxf(m, pm);
      float sf = exp2f(m - mn);
      m = mn;
      l *= sf;
#pragma unroll
      for (int dt = 0; dt < 4; ++dt)
#pragma unroll
        for (int e = 0; e < 4; ++e) o[dt][e] *= sf;
    }

    f32x4 p[4];
#pragma unroll
    for (int tt = 0; tt < 4; ++tt)
#pragma unroll
      for (int e = 0; e < 4; ++e) p[tt][e] = exp2f(s[tt][e] - m);
    // pack pairs (1 inst each) and store P[q=r][kv] as 4 x ds_write_b64
#pragma unroll
    for (int tt = 0; tt < 4; ++tt) {
      u32x2 w;
      w[0] = cvtpk(p[tt][0], p[tt][1]);
      w[1] = cvtpk(p[tt][2], p[tt][3]);
      *(u32x2*)&pw[r * 72 + tt * 16 + g * 4] = w;
    }
    f32x4 s4;
#pragma unroll
    for (int e = 0; e < 4; ++e)
      s4[e] = (p[0][e] + p[1][e]) + (p[2][e] + p[3][e]);
    float rs = (s4[0] + s4[1]) + (s4[2] + s4[3]);
    rs += __shfl_xor(rs, 16);
    rs += __shfl_xor(rs, 32);
    l += rs;

    // ---- PV: O^T[d][q] += V^T[d][kv] * P^T[kv][q] ----
    bf16x8 pB0 = *(const bf16x8*)&pw[r * 72 + g * 8];
    bf16x8 pB1 = *(const bf16x8*)&pw[r * 72 + 32 + g * 8];
#pragma unroll
    for (int dt = 0; dt < 4; ++dt) {
      bf16x8 v0 = *(const bf16x8*)&Vs[cur][dt * 16 + r][((0 + g) ^ (r & 7)) * 8];
      bf16x8 v1 = *(const bf16x8*)&Vs[cur][dt * 16 + r][((4 + g) ^ (r & 7)) * 8];
      o[dt] = __builtin_amdgcn_mfma_f32_16x16x32_bf16(v0, pB0, o[dt], 0, 0, 0);
      o[dt] = __builtin_amdgcn_mfma_f32_16x16x32_bf16(v1, pB1, o[dt], 0, 0, 0);
    }
  }

  // ---- epilogue: lane holds O^T[d=dt*16+g*4+e][q=r]; write O[s][h*64+d] ----
  float inv = 1.f / l;
  size_t rowbase = ((size_t)b * 2048 + qw + r) * 1024 + h * 64;
#pragma unroll
  for (int dt = 0; dt < 4; ++dt) {
    u16x4 ov;
#pragma unroll
    for (int e = 0; e < 4; ++e) ov[e] = f2bf(o[dt][e] * inv);
    *(u16x4*)&O[rowbase + dt * 16 + g * 4] = ov;
  }
}

extern "C" void kernel_launch(void* const* d_in, const int* in_sizes, int n_in,
                              void* d_out, int out_size, void* d_ws,
                              size_t ws_size, hipStream_t stream) {
  const float* x = (const float*)d_in[0];
  const float* wqkv = (const float*)d_in[1];
  const float* wout = (const float*)d_in[2];
  float* out = (float*)d_out;
  char* ws = (char*)d_ws;

  // workspace layout (bytes)
  u16* Xb = (u16*)ws;                          // 16 MB [8192][1024] (later: attn out)
  u16* Wt = (u16*)(ws + (16ull << 20));        // 6 MB [3072][1024]
  u16* WoT = (u16*)(ws + (22ull << 20));       // 2 MB [1024][1024]
  u16* Qb = (u16*)(ws + (24ull << 20));        // 16 MB [B*H][2048][64]
  u16* Kb = (u16*)(ws + (40ull << 20));        // 16 MB
  u16* Vt = (u16*)(ws + (56ull << 20));        // 16 MB [1024][8192]

  convx<<<4096, 256, 0, stream>>>((const float4*)x, (u16x8*)Xb, 1048576);
  transpose_w<<<dim3(96, 32), 256, 0, stream>>>(wqkv, Wt, 1024, 3072);
  transpose_w<<<dim3(32, 32), 256, 0, stream>>>(wout, WoT, 1024, 1024);

  // Q,K: [8192,1024] x [1024,2048] -> scatter (Q pre-scaled)
  gemm_bt<1><<<dim3(16, 64), 256, 0, stream>>>(Xb, Wt, nullptr, 8192, 2048,
                                               1024, Qb, Kb);
  // V^T: Wv^T [1024,1024] x Xb^T -> Vt [1024][8192]
  gemm_bt<0><<<dim3(64, 8), 256, 0, stream>>>(Wt + (size_t)2048 * 1024, Xb, Vt,
                                              1024, 8192, 1024, nullptr, nullptr);
  // attention; writes bf16 attn output into Xb (dead after V-GEMM)
  attn_fwd<<<dim3(64, 16), 512, 0, stream>>>(Qb, Kb, Vt, Xb);
  // out = attn @ w_out : [8192,1024] x [1024,1024] -> fp32
  gemm_bt<2><<<dim3(8, 64), 256, 0, stream>>>(Xb, WoT, out, 8192, 1024, 1024,
                                              nullptr, nullptr);
}